// Round 1
// baseline (233.207 us; speedup 1.0000x reference)
//
#include <hip/hip_runtime.h>
#include <hip/hip_bf16.h>

#define EMBED 1024
#define SEQ   4096
#define NBATCH 4
#define HD    64

typedef __attribute__((ext_vector_type(8))) short s16x8;
typedef __attribute__((ext_vector_type(4))) float f32x4;

__device__ __forceinline__ short f2bf(float f) {
    unsigned u = __builtin_bit_cast(unsigned, f);
    u += 0x7fffu + ((u >> 16) & 1u);      // round-to-nearest-even
    return (short)(u >> 16);
}
__device__ __forceinline__ float bf2f(short h) {
    unsigned u = ((unsigned)(unsigned short)h) << 16;
    return __builtin_bit_cast(float, u);
}

typedef const unsigned int __attribute__((address_space(1)))* gbl_ptr_t;
typedef unsigned int __attribute__((address_space(3)))* lds_ptr_t;
__device__ __forceinline__ void async16(const void* g, void* l) {
    __builtin_amdgcn_global_load_lds((gbl_ptr_t)g, (lds_ptr_t)l, 16, 0, 0);
}

// ---------------------------------------------------------------------------
// Kernel 1: QKV projection.  emb[16384][1024] fp32 x W{q,k,v}[64][1024] fp32
//  -> Qb[b][s][64] bf16 (pre-scaled by 0.125), Kb[b][s][64] bf16,
//     Vt[b][64][s] bf16 (transposed for PV B-operand reads).
// BM=32 rows, BN=192 cols (Q|K|V), BK=64. 4 waves: (wr,wc) 2x2, each 16x96.
// ---------------------------------------------------------------------------
__global__ __launch_bounds__(256) void proj_qkv(
    const float* __restrict__ emb,
    const float* __restrict__ wq, const float* __restrict__ wk,
    const float* __restrict__ wv,
    short* __restrict__ Qb, short* __restrict__ Kb, short* __restrict__ Vt)
{
    __shared__ short Alds[32 * 64];   // 4 KB, 16B-block XOR swizzled
    __shared__ short Blds[192 * 64];  // 24 KB

    const int tid  = threadIdx.x;
    const int lane = tid & 63;
    const int w    = tid >> 6;
    const int wr   = w & 1;
    const int wc   = w >> 1;
    const int row0 = blockIdx.x * 32;

    f32x4 acc[6];
#pragma unroll
    for (int i = 0; i < 6; ++i) acc[i] = f32x4{0.f, 0.f, 0.f, 0.f};

    const int sr = tid >> 3;   // staging row 0..31
    const int sg = tid & 7;    // staging 16B block 0..7

    for (int k0 = 0; k0 < EMBED; k0 += 64) {
        __syncthreads();
        { // stage A tile: 32 rows x 64 k, fp32 -> bf16
            const float* src = emb + (size_t)(row0 + sr) * EMBED + k0 + sg * 8;
            float4 f0 = *(const float4*)src;
            float4 f1 = *(const float4*)(src + 4);
            s16x8 v = { f2bf(f0.x), f2bf(f0.y), f2bf(f0.z), f2bf(f0.w),
                        f2bf(f1.x), f2bf(f1.y), f2bf(f1.z), f2bf(f1.w) };
            *(s16x8*)&Alds[sr * 64 + ((sg ^ (sr & 7)) * 8)] = v;
        }
#pragma unroll
        for (int p = 0; p < 6; ++p) { // stage B tile: 192 rows x 64 k
            int r = p * 32 + sr;
            int mat = r >> 6, rr = r & 63;
            const float* wsrc = (mat == 0 ? wq : (mat == 1 ? wk : wv))
                                + (size_t)rr * EMBED + k0 + sg * 8;
            float4 f0 = *(const float4*)wsrc;
            float4 f1 = *(const float4*)(wsrc + 4);
            s16x8 v = { f2bf(f0.x), f2bf(f0.y), f2bf(f0.z), f2bf(f0.w),
                        f2bf(f1.x), f2bf(f1.y), f2bf(f1.z), f2bf(f1.w) };
            *(s16x8*)&Blds[r * 64 + ((sg ^ (r & 7)) * 8)] = v;
        }
        __syncthreads();

        const int ar = wr * 16 + (lane & 15);
        const int ag = lane >> 4;                    // k-group 0..3
        s16x8 a0 = *(const s16x8*)&Alds[ar * 64 + (((ag    ) ^ (ar & 7)) * 8)];
        s16x8 a1 = *(const s16x8*)&Alds[ar * 64 + (((ag + 4) ^ (ar & 7)) * 8)];
#pragma unroll
        for (int n = 0; n < 6; ++n) {
            int br = wc * 96 + n * 16 + (lane & 15);
            s16x8 b0 = *(const s16x8*)&Blds[br * 64 + (((ag    ) ^ (br & 7)) * 8)];
            s16x8 b1 = *(const s16x8*)&Blds[br * 64 + (((ag + 4) ^ (br & 7)) * 8)];
            acc[n] = __builtin_amdgcn_mfma_f32_16x16x32_bf16(a0, b0, acc[n], 0, 0, 0);
            acc[n] = __builtin_amdgcn_mfma_f32_16x16x32_bf16(a1, b1, acc[n], 0, 0, 0);
        }
    }

    // epilogue: C layout col=lane&15, row=(lane>>4)*4+reg  [verified m89]
    const int rbase = row0 + wr * 16 + ((lane >> 4) * 4);
    const int cl = lane & 15;
#pragma unroll
    for (int n = 0; n < 6; ++n) {
        int col = wc * 96 + n * 16 + cl;   // 0..191
        int mat = col >> 6;
        int c = col & 63;
#pragma unroll
        for (int r = 0; r < 4; ++r) {
            int row = rbase + r;
            int b = row >> 12, s = row & 4095;
            float v = acc[n][r];
            if (mat == 0)       Qb[((size_t)b * SEQ + s) * HD + c] = f2bf(v * 0.125f);
            else if (mat == 1)  Kb[((size_t)b * SEQ + s) * HD + c] = f2bf(v);
            else                Vt[((size_t)b * HD + c) * SEQ + s] = f2bf(v);
        }
    }
}

// ---------------------------------------------------------------------------
// Kernel 2: causal flash attention. QBLK=64, KVBLK=64, 4 waves x 16 q-rows.
// ---------------------------------------------------------------------------
__global__ __launch_bounds__(256) void attn_fwd(
    const short* __restrict__ Qb, const short* __restrict__ Kb,
    const short* __restrict__ Vt, float* __restrict__ out)
{
    __shared__ short Qlds[64 * 64];  // [q][d]  swizzled
    __shared__ short Klds[64 * 64];  // [kv][d] swizzled
    __shared__ short Vlds[64 * 64];  // [d][kv] swizzled (from Vt)
    __shared__ short Plds[64 * 64];  // [q][kv] per-wave 16-row regions

    const int tid  = threadIdx.x;
    const int lane = tid & 63;
    const int w    = tid >> 6;
    const int jq   = blockIdx.x;     // q-tile 0..63
    const int b    = blockIdx.y;
    const int q0   = jq * 64;

    const short* Qbase  = Qb + ((size_t)b * SEQ + q0) * HD;
    const short* Kbase0 = Kb + (size_t)b * SEQ * HD;
    const short* Vbase0 = Vt + (size_t)b * HD * SEQ;

    const int srow = lane >> 3;   // 0..7 within 8-row chunk
    const int sblk = lane & 7;    // 16B block 0..7

    // stage Q tile: pre-swizzled global source, linear LDS dest (rule #21)
#pragma unroll
    for (int i = 0; i < 2; ++i) {
        int r = w * 16 + i * 8 + srow;
        async16(Qbase + (size_t)r * HD + ((sblk ^ (r & 7)) * 8),
                &Qlds[(w * 16 + i * 8) * 64]);
    }
    __syncthreads();

    const int qrow = w * 16 + (lane & 15);
    const int ag = lane >> 4;
    s16x8 qa0 = *(const s16x8*)&Qlds[qrow * 64 + (((ag    ) ^ (qrow & 7)) * 8)];
    s16x8 qa1 = *(const s16x8*)&Qlds[qrow * 64 + (((ag + 4) ^ (qrow & 7)) * 8)];

    f32x4 o[4];
#pragma unroll
    for (int n = 0; n < 4; ++n) o[n] = f32x4{0.f, 0.f, 0.f, 0.f};
    float m[4], l[4];
#pragma unroll
    for (int r = 0; r < 4; ++r) { m[r] = -INFINITY; l[r] = 0.f; }

    for (int j = 0; j <= jq; ++j) {
        const int kv0 = j * 64;
#pragma unroll
        for (int i = 0; i < 2; ++i) {
            int r = w * 16 + i * 8 + srow;
            async16(Kbase0 + (size_t)(kv0 + r) * HD + ((sblk ^ (r & 7)) * 8),
                    &Klds[(w * 16 + i * 8) * 64]);
            async16(Vbase0 + (size_t)r * SEQ + kv0 + ((sblk ^ (r & 7)) * 8),
                    &Vlds[(w * 16 + i * 8) * 64]);
        }
        __syncthreads();   // drains vmcnt (global_load_lds) + orders LDS

        // S = Q K^T : per wave 16q x 64kv, contraction d=64
        f32x4 s[4];
#pragma unroll
        for (int n = 0; n < 4; ++n) {
            int kr = n * 16 + (lane & 15);
            s16x8 b0 = *(const s16x8*)&Klds[kr * 64 + (((ag    ) ^ (kr & 7)) * 8)];
            s16x8 b1 = *(const s16x8*)&Klds[kr * 64 + (((ag + 4) ^ (kr & 7)) * 8)];
            s[n] = __builtin_amdgcn_mfma_f32_16x16x32_bf16(qa0, b0, f32x4{0.f,0.f,0.f,0.f}, 0, 0, 0);
            s[n] = __builtin_amdgcn_mfma_f32_16x16x32_bf16(qa1, b1, s[n], 0, 0, 0);
        }

        if (j == jq) { // causal mask on diagonal tile
            int qg = q0 + w * 16 + ((lane >> 4) * 4);
#pragma unroll
            for (int n = 0; n < 4; ++n) {
                int kvg = kv0 + n * 16 + (lane & 15);
#pragma unroll
                for (int r = 0; r < 4; ++r)
                    if (kvg > qg + r) s[n][r] = -INFINITY;
            }
        }

        // online softmax: rows live on 16-lane groups (xor 1,2,4,8)
        float mt[4];
#pragma unroll
        for (int r = 0; r < 4; ++r)
            mt[r] = fmaxf(fmaxf(s[0][r], s[1][r]), fmaxf(s[2][r], s[3][r]));
#pragma unroll
        for (int d = 1; d < 16; d <<= 1) {
#pragma unroll
            for (int r = 0; r < 4; ++r)
                mt[r] = fmaxf(mt[r], __shfl_xor(mt[r], d, 64));
        }
        float fac[4];
#pragma unroll
        for (int r = 0; r < 4; ++r) {
            float mn = fmaxf(m[r], mt[r]);
            fac[r] = __expf(m[r] - mn);
            m[r] = mn;
        }
        float rs[4] = {0.f, 0.f, 0.f, 0.f};
        // p = exp(s-m); write bf16 P to per-wave LDS region; accumulate the
        // QUANTIZED p into the denominator so numerator/denominator match.
#pragma unroll
        for (int n = 0; n < 4; ++n) {
#pragma unroll
            for (int r = 0; r < 4; ++r) {
                float p = __expf(s[n][r] - m[r]);
                short pb = f2bf(p);
                rs[r] += bf2f(pb);
                int q  = w * 16 + ((lane >> 4) * 4) + r;
                int kv = n * 16 + (lane & 15);
                Plds[q * 64 + (((kv >> 3) ^ (q & 7)) * 8) + (kv & 7)] = pb;
            }
        }
#pragma unroll
        for (int d = 1; d < 16; d <<= 1) {
#pragma unroll
            for (int r = 0; r < 4; ++r)
                rs[r] += __shfl_xor(rs[r], d, 64);
        }
#pragma unroll
        for (int r = 0; r < 4; ++r) l[r] = l[r] * fac[r] + rs[r];
#pragma unroll
        for (int n = 0; n < 4; ++n)
#pragma unroll
            for (int r = 0; r < 4; ++r) o[n][r] *= fac[r];

        // O += P V  (A=P from per-wave LDS, B=V via Vt rows: contiguous kv)
#pragma unroll
        for (int kk = 0; kk < 2; ++kk) {
            int pr = w * 16 + (lane & 15);
            s16x8 pa = *(const s16x8*)&Plds[pr * 64 + ((((ag + kk * 4)) ^ (pr & 7)) * 8)];
#pragma unroll
            for (int n = 0; n < 4; ++n) {
                int vr = n * 16 + (lane & 15);
                s16x8 vb = *(const s16x8*)&Vlds[vr * 64 + (((ag + kk * 4) ^ (vr & 7)) * 8)];
                o[n] = __builtin_amdgcn_mfma_f32_16x16x32_bf16(pa, vb, o[n], 0, 0, 0);
            }
        }
        __syncthreads();   // all waves done with K/V before next stage
    }

    // epilogue: out[b][q][h] fp32
    float* obase = out + ((size_t)b * SEQ + q0) * HD;
#pragma unroll
    for (int r = 0; r < 4; ++r) {
        int q = w * 16 + ((lane >> 4) * 4) + r;
        float inv = 1.0f / l[r];
#pragma unroll
        for (int n = 0; n < 4; ++n)
            obase[(size_t)q * HD + n * 16 + (lane & 15)] = o[n][r] * inv;
    }
}

// ---------------------------------------------------------------------------
extern "C" void kernel_launch(void* const* d_in, const int* in_sizes, int n_in,
                              void* d_out, int out_size, void* d_ws, size_t ws_size,
                              hipStream_t stream)
{
    (void)in_sizes; (void)n_in; (void)out_size; (void)ws_size;
    const float* emb = (const float*)d_in[0];
    const float* wq  = (const float*)d_in[1];
    const float* wk  = (const float*)d_in[2];
    const float* wv  = (const float*)d_in[3];
    float* out = (float*)d_out;

    short* Qb = (short*)d_ws;                          // [4][4096][64] bf16
    short* Kb = Qb + (size_t)NBATCH * SEQ * HD;        // [4][4096][64] bf16
    short* Vt = Kb + (size_t)NBATCH * SEQ * HD;        // [4][64][4096] bf16

    hipLaunchKernelGGL(proj_qkv, dim3(512), dim3(256), 0, stream,
                       emb, wq, wk, wv, Qb, Kb, Vt);
    hipLaunchKernelGGL(attn_fwd, dim3(64, NBATCH), dim3(256), 0, stream,
                       Qb, Kb, Vt, out);
}

// Round 2
// 166.507 us; speedup vs baseline: 1.4006x; 1.4006x over previous
//
#include <hip/hip_runtime.h>
#include <hip/hip_bf16.h>

#define EMBED 1024
#define SEQ   4096
#define NBATCH 4
#define HD    64
#define CHUNK 16   // kv tiles (of 64) per attention partition

typedef __attribute__((ext_vector_type(8))) short s16x8;
typedef __attribute__((ext_vector_type(4))) float f32x4;

__device__ __forceinline__ short f2bf(float f) {
    unsigned u = __builtin_bit_cast(unsigned, f);
    u += 0x7fffu + ((u >> 16) & 1u);      // round-to-nearest-even
    return (short)(u >> 16);
}
__device__ __forceinline__ float bf2f(short h) {
    unsigned u = ((unsigned)(unsigned short)h) << 16;
    return __builtin_bit_cast(float, u);
}

typedef const unsigned int __attribute__((address_space(1)))* gbl_ptr_t;
typedef unsigned int __attribute__((address_space(3)))* lds_ptr_t;
__device__ __forceinline__ void async16(const void* g, void* l) {
    __builtin_amdgcn_global_load_lds((gbl_ptr_t)g, (lds_ptr_t)l, 16, 0, 0);
}

// ---------------------------------------------------------------------------
// Kernel 0: convert W_Q (pre-scaled by 1/8), W_K, W_V fp32 -> bf16 Wb[192][1024]
// ---------------------------------------------------------------------------
__global__ __launch_bounds__(256) void prep_w(
    const float* __restrict__ wq, const float* __restrict__ wk,
    const float* __restrict__ wv, short* __restrict__ Wb)
{
    int idx = blockIdx.x * 256 + threadIdx.x;   // 24576 threads, 8 elems each
    int e = idx * 8;
    int row = e >> 10, col = e & 1023;
    const float* src = (row < 64) ? (wq + (size_t)row * EMBED)
                     : (row < 128) ? (wk + (size_t)(row - 64) * EMBED)
                                   : (wv + (size_t)(row - 128) * EMBED);
    float sc = (row < 64) ? 0.125f : 1.0f;
    float4 f0 = *(const float4*)(src + col);
    float4 f1 = *(const float4*)(src + col + 4);
    s16x8 v = { f2bf(f0.x*sc), f2bf(f0.y*sc), f2bf(f0.z*sc), f2bf(f0.w*sc),
                f2bf(f1.x*sc), f2bf(f1.y*sc), f2bf(f1.z*sc), f2bf(f1.w*sc) };
    *(s16x8*)&Wb[e] = v;
}

// ---------------------------------------------------------------------------
// Kernel 1: QKV projection (double-buffered).
//  A: emb fp32 -> regs (issued early) -> convert -> swizzled ds_write
//  B: Wb bf16 staged via global_load_lds (pre-swizzled source, linear dest)
// BM=32, BN=192, BK=64; 4 waves (wr,wc) 2x2, each 16x96; K-loop 16 iters.
// ---------------------------------------------------------------------------
__global__ __launch_bounds__(256) void proj_qkv(
    const float* __restrict__ emb, const short* __restrict__ Wb,
    short* __restrict__ Qb, short* __restrict__ Kb, short* __restrict__ Vt)
{
    __shared__ short Alds[2][32 * 64];    // 2 x 4 KB
    __shared__ short Blds[2][192 * 64];   // 2 x 24 KB

    const int tid  = threadIdx.x;
    const int lane = tid & 63;
    const int w    = tid >> 6;
    const int wr   = w & 1;
    const int wc   = w >> 1;
    const int row0 = blockIdx.x * 32;

    const int sr   = tid >> 3;     // block staging row 0..31
    const int sg   = tid & 7;      // 16B group 0..7
    const int srow = lane >> 3;    // wave staging row 0..7
    const int sblk = lane & 7;

    f32x4 acc[6];
#pragma unroll
    for (int i = 0; i < 6; ++i) acc[i] = f32x4{0.f, 0.f, 0.f, 0.f};

    auto stageB = [&](int buf, int t) {
        const int k0 = t * 64;
#pragma unroll
        for (int i = 0; i < 6; ++i) {
            int r = w * 48 + i * 8 + srow;
            async16(Wb + (size_t)r * EMBED + k0 + ((sblk ^ (r & 7)) * 8),
                    &Blds[buf][(w * 48 + i * 8) * 64]);
        }
    };

    // prologue: tile 0 into buf 0
    {
        const float* asrc = emb + (size_t)(row0 + sr) * EMBED + sg * 8;
        float4 f0 = *(const float4*)asrc;
        float4 f1 = *(const float4*)(asrc + 4);
        s16x8 v = { f2bf(f0.x), f2bf(f0.y), f2bf(f0.z), f2bf(f0.w),
                    f2bf(f1.x), f2bf(f1.y), f2bf(f1.z), f2bf(f1.w) };
        *(s16x8*)&Alds[0][sr * 64 + ((sg ^ (sr & 7)) * 8)] = v;
        stageB(0, 0);
    }
    __syncthreads();

    int cur = 0;
    const int ar = wr * 16 + (lane & 15);
    const int ag = lane >> 4;

    for (int t = 0; t < 16; ++t) {
        float4 f0n, f1n;
        const bool more = (t + 1 < 16);
        if (more) {   // issue next A loads early (T14) + next B async stage
            const float* asrc = emb + (size_t)(row0 + sr) * EMBED + (t + 1) * 64 + sg * 8;
            f0n = *(const float4*)asrc;
            f1n = *(const float4*)(asrc + 4);
            stageB(cur ^ 1, t + 1);
        }
        // compute on buf cur
        s16x8 a0 = *(const s16x8*)&Alds[cur][ar * 64 + (((ag    ) ^ (ar & 7)) * 8)];
        s16x8 a1 = *(const s16x8*)&Alds[cur][ar * 64 + (((ag + 4) ^ (ar & 7)) * 8)];
#pragma unroll
        for (int n = 0; n < 6; ++n) {
            int br = wc * 96 + n * 16 + (lane & 15);
            s16x8 b0 = *(const s16x8*)&Blds[cur][br * 64 + (((ag    ) ^ (br & 7)) * 8)];
            s16x8 b1 = *(const s16x8*)&Blds[cur][br * 64 + (((ag + 4) ^ (br & 7)) * 8)];
            acc[n] = __builtin_amdgcn_mfma_f32_16x16x32_bf16(a0, b0, acc[n], 0, 0, 0);
            acc[n] = __builtin_amdgcn_mfma_f32_16x16x32_bf16(a1, b1, acc[n], 0, 0, 0);
        }
        if (more) {   // convert + write next A tile (latency already hidden)
            s16x8 v = { f2bf(f0n.x), f2bf(f0n.y), f2bf(f0n.z), f2bf(f0n.w),
                        f2bf(f1n.x), f2bf(f1n.y), f2bf(f1n.z), f2bf(f1n.w) };
            *(s16x8*)&Alds[cur ^ 1][sr * 64 + ((sg ^ (sr & 7)) * 8)] = v;
        }
        __syncthreads();
        cur ^= 1;
    }

    // epilogue: C layout col=lane&15, row=(lane>>4)*4+reg
    const int rbase = row0 + wr * 16 + ((lane >> 4) * 4);
    const int cl = lane & 15;
#pragma unroll
    for (int n = 0; n < 6; ++n) {
        int col = wc * 96 + n * 16 + cl;   // 0..191
        int mat = col >> 6;
        int c = col & 63;
#pragma unroll
        for (int r = 0; r < 4; ++r) {
            int row = rbase + r;
            int b = row >> 12, s = row & 4095;
            short v = f2bf(acc[n][r]);
            if (mat == 0)       Qb[((size_t)b * SEQ + s) * HD + c] = v;
            else if (mat == 1)  Kb[((size_t)b * SEQ + s) * HD + c] = v;
            else                Vt[((size_t)b * HD + c) * SEQ + s] = v;
        }
    }
}

// ---------------------------------------------------------------------------
// Kernel 2: causal flash attention, KV-partitioned (flash-decoding).
// Block (jq, b, p): q-tile jq (64 rows), kv tiles [p*CHUNK, min((p+1)*CHUNK, jq+1)).
// Double-buffered K/V staging, one barrier/iter. Writes unnormalized partials.
// ---------------------------------------------------------------------------
__global__ __launch_bounds__(256) void attn_fwd(
    const short* __restrict__ Qb, const short* __restrict__ Kb,
    const short* __restrict__ Vt, float* __restrict__ Op, float* __restrict__ Ml)
{
    const int jq = blockIdx.x;       // q-tile 0..63
    const int b  = blockIdx.y;
    const int p  = blockIdx.z;       // partition 0..3
    const int ntiles = jq + 1;
    const int t0 = p * CHUNK;
    if (t0 >= ntiles) return;        // inactive partition (uniform exit)
    const int t1 = min(t0 + CHUNK, ntiles);

    __shared__ short Qlds[64 * 64];        // 8 KB
    __shared__ short Klds[2][64 * 64];     // 16 KB
    __shared__ short Vlds[2][64 * 64];     // 16 KB
    __shared__ short Plds[64 * 64];        // 8 KB (per-wave 16-row regions)

    const int tid  = threadIdx.x;
    const int lane = tid & 63;
    const int w    = tid >> 6;
    const int q0   = jq * 64;

    const short* Qbase  = Qb + ((size_t)b * SEQ + q0) * HD;
    const short* Kbase0 = Kb + (size_t)b * SEQ * HD;
    const short* Vbase0 = Vt + (size_t)b * HD * SEQ;

    const int srow = lane >> 3;
    const int sblk = lane & 7;

    auto stageKV = [&](int buf, int t) {
        const int kv0 = t * 64;
#pragma unroll
        for (int i = 0; i < 2; ++i) {
            int r = w * 16 + i * 8 + srow;
            async16(Kbase0 + (size_t)(kv0 + r) * HD + ((sblk ^ (r & 7)) * 8),
                    &Klds[buf][(w * 16 + i * 8) * 64]);
            async16(Vbase0 + (size_t)r * SEQ + kv0 + ((sblk ^ (r & 7)) * 8),
                    &Vlds[buf][(w * 16 + i * 8) * 64]);
        }
    };

    // prologue: Q tile + first K/V tile
#pragma unroll
    for (int i = 0; i < 2; ++i) {
        int r = w * 16 + i * 8 + srow;
        async16(Qbase + (size_t)r * HD + ((sblk ^ (r & 7)) * 8),
                &Qlds[(w * 16 + i * 8) * 64]);
    }
    stageKV(0, t0);
    __syncthreads();

    const int qrow = w * 16 + (lane & 15);
    const int ag = lane >> 4;
    s16x8 qa0 = *(const s16x8*)&Qlds[qrow * 64 + (((ag    ) ^ (qrow & 7)) * 8)];
    s16x8 qa1 = *(const s16x8*)&Qlds[qrow * 64 + (((ag + 4) ^ (qrow & 7)) * 8)];

    f32x4 o[4];
#pragma unroll
    for (int n = 0; n < 4; ++n) o[n] = f32x4{0.f, 0.f, 0.f, 0.f};
    float m[4], l[4];
#pragma unroll
    for (int r = 0; r < 4; ++r) { m[r] = -INFINITY; l[r] = 0.f; }

    int cur = 0;
    for (int t = t0; t < t1; ++t) {
        if (t + 1 < t1) stageKV(cur ^ 1, t + 1);   // prefetch next tile

        const int kv0 = t * 64;
        f32x4 s[4];
#pragma unroll
        for (int n = 0; n < 4; ++n) {
            int kr = n * 16 + (lane & 15);
            s16x8 b0 = *(const s16x8*)&Klds[cur][kr * 64 + (((ag    ) ^ (kr & 7)) * 8)];
            s16x8 b1 = *(const s16x8*)&Klds[cur][kr * 64 + (((ag + 4) ^ (kr & 7)) * 8)];
            s[n] = __builtin_amdgcn_mfma_f32_16x16x32_bf16(qa0, b0, f32x4{0.f,0.f,0.f,0.f}, 0, 0, 0);
            s[n] = __builtin_amdgcn_mfma_f32_16x16x32_bf16(qa1, b1, s[n], 0, 0, 0);
        }

        if (t == jq) { // causal mask: only the diagonal tile
            int qg = q0 + w * 16 + ((lane >> 4) * 4);
#pragma unroll
            for (int n = 0; n < 4; ++n) {
                int kvg = kv0 + n * 16 + (lane & 15);
#pragma unroll
                for (int r = 0; r < 4; ++r)
                    if (kvg > qg + r) s[n][r] = -INFINITY;
            }
        }

        // online softmax (rows on 16-lane groups)
        float mt[4];
#pragma unroll
        for (int r = 0; r < 4; ++r)
            mt[r] = fmaxf(fmaxf(s[0][r], s[1][r]), fmaxf(s[2][r], s[3][r]));
#pragma unroll
        for (int d = 1; d < 16; d <<= 1) {
#pragma unroll
            for (int r = 0; r < 4; ++r)
                mt[r] = fmaxf(mt[r], __shfl_xor(mt[r], d, 64));
        }
        float fac[4];
#pragma unroll
        for (int r = 0; r < 4; ++r) {
            float mn = fmaxf(m[r], mt[r]);
            fac[r] = __expf(m[r] - mn);
            m[r] = mn;
        }
        float rs[4] = {0.f, 0.f, 0.f, 0.f};
#pragma unroll
        for (int n = 0; n < 4; ++n) {
#pragma unroll
            for (int r = 0; r < 4; ++r) {
                float pv = __expf(s[n][r] - m[r]);
                short pb = f2bf(pv);
                rs[r] += bf2f(pb);
                int q  = w * 16 + ((lane >> 4) * 4) + r;
                int kv = n * 16 + (lane & 15);
                Plds[q * 64 + (((kv >> 3) ^ (q & 7)) * 8) + (kv & 7)] = pb;
            }
        }
#pragma unroll
        for (int d = 1; d < 16; d <<= 1) {
#pragma unroll
            for (int r = 0; r < 4; ++r)
                rs[r] += __shfl_xor(rs[r], d, 64);
        }
#pragma unroll
        for (int r = 0; r < 4; ++r) l[r] = l[r] * fac[r] + rs[r];
#pragma unroll
        for (int n = 0; n < 4; ++n)
#pragma unroll
            for (int r = 0; r < 4; ++r) o[n][r] *= fac[r];

        // O += P V
#pragma unroll
        for (int kk = 0; kk < 2; ++kk) {
            int pr = w * 16 + (lane & 15);
            s16x8 pa = *(const s16x8*)&Plds[pr * 64 + (((ag + kk * 4) ^ (pr & 7)) * 8)];
#pragma unroll
            for (int n = 0; n < 4; ++n) {
                int vr = n * 16 + (lane & 15);
                s16x8 vb = *(const s16x8*)&Vlds[cur][vr * 64 + (((ag + kk * 4) ^ (vr & 7)) * 8)];
                o[n] = __builtin_amdgcn_mfma_f32_16x16x32_bf16(pa, vb, o[n], 0, 0, 0);
            }
        }
        __syncthreads();   // staged t+1 ready; all waves done with cur
        cur ^= 1;
    }

    // write partials (unnormalized O, plus m & l per row)
    float* opbase = Op + (((size_t)b * 64 + jq) * 4 + p) * 64 * 64;
    float* mlbase = Ml + (((size_t)b * 64 + jq) * 4 + p) * 64 * 2;
#pragma unroll
    for (int r = 0; r < 4; ++r) {
        int ql = w * 16 + ((lane >> 4) * 4) + r;
        if ((lane & 15) == 0) {
            mlbase[ql * 2]     = m[r];
            mlbase[ql * 2 + 1] = l[r];
        }
#pragma unroll
        for (int n = 0; n < 4; ++n)
            opbase[(size_t)ql * 64 + n * 16 + (lane & 15)] = o[n][r];
    }
}

// ---------------------------------------------------------------------------
// Kernel 3: merge <=4 partials per (b, q-tile) -> normalized output fp32
// ---------------------------------------------------------------------------
__global__ __launch_bounds__(256) void attn_combine(
    const float* __restrict__ Op, const float* __restrict__ Ml,
    float* __restrict__ out)
{
    const int jq = blockIdx.x;
    const int b  = blockIdx.y;
    const int nP = (jq >> 4) + 1;
    const int tid = threadIdx.x;
    const int row = tid >> 2;
    const int c0  = (tid & 3) * 16;
    const size_t pb = ((size_t)b * 64 + jq) * 4;

    float mv[4], lv[4], wt[4];
    float mstar = -INFINITY;
#pragma unroll
    for (int p = 0; p < 4; ++p) if (p < nP) {
        mv[p] = Ml[(pb + p) * 128 + row * 2];
        lv[p] = Ml[(pb + p) * 128 + row * 2 + 1];
        mstar = fmaxf(mstar, mv[p]);
    }
    float L = 0.f;
#pragma unroll
    for (int p = 0; p < 4; ++p) if (p < nP) {
        wt[p] = __expf(mv[p] - mstar);
        L += lv[p] * wt[p];
    }
    float inv = 1.0f / L;

    float acc[16];
#pragma unroll
    for (int k = 0; k < 16; ++k) acc[k] = 0.f;
#pragma unroll
    for (int p = 0; p < 4; ++p) if (p < nP) {
        const float* src = &Op[((pb + p) * 64 + row) * 64 + c0];
#pragma unroll
        for (int k = 0; k < 16; ++k) acc[k] += src[k] * wt[p];
    }
    float* dst = out + ((size_t)b * SEQ + jq * 64 + row) * HD + c0;
#pragma unroll
    for (int k = 0; k < 16; ++k) dst[k] = acc[k] * inv;
}

// ---------------------------------------------------------------------------
extern "C" void kernel_launch(void* const* d_in, const int* in_sizes, int n_in,
                              void* d_out, int out_size, void* d_ws, size_t ws_size,
                              hipStream_t stream)
{
    (void)in_sizes; (void)n_in; (void)out_size; (void)ws_size;
    const float* emb = (const float*)d_in[0];
    const float* wq  = (const float*)d_in[1];
    const float* wk  = (const float*)d_in[2];
    const float* wv  = (const float*)d_in[3];
    float* out = (float*)d_out;

    short* Wb = (short*)d_ws;                          // [192][1024] bf16 (WQ pre-scaled)
    short* Qb = Wb + 192 * 1024;                       // [4][4096][64] bf16
    short* Kb = Qb + (size_t)NBATCH * SEQ * HD;        // [4][4096][64] bf16
    short* Vt = Kb + (size_t)NBATCH * SEQ * HD;        // [4][64][4096] bf16
    float* Op = (float*)(Vt + (size_t)NBATCH * SEQ * HD);  // [4][64][4][64][64] f32
    float* Ml = Op + (size_t)NBATCH * 64 * 4 * 64 * 64;    // [4][64][4][64][2] f32

    hipLaunchKernelGGL(prep_w, dim3(96), dim3(256), 0, stream, wq, wk, wv, Wb);
    hipLaunchKernelGGL(proj_qkv, dim3(512), dim3(256), 0, stream, emb, Wb, Qb, Kb, Vt);
    hipLaunchKernelGGL(attn_fwd, dim3(64, NBATCH, 4), dim3(256), 0, stream,
                       Qb, Kb, Vt, Op, Ml);
    hipLaunchKernelGGL(attn_combine, dim3(64, NBATCH), dim3(256), 0, stream,
                       Op, Ml, out);
}